// Round 3
// baseline (370.700 us; speedup 1.0000x reference)
//
#include <hip/hip_runtime.h>

// SimpleHashEncoder1D: out[n, l*2+f] = hash_table[floor(xn*scale[l]+0.5) & (T-1)][f]
// xn = (x+bound)/(2*bound), scale[l] = 16*b^l - 1, b = expf((logf(2^19)-logf(16))/15)
//
// float32 bit-exactness (verified R1, absmax == 0.0):
//   b = 0x3FFFFFFF = 2 - 2^-23   (NOT 2.0: correctly-rounded f32 log/exp chain)
//   fl32(b^l) = 2^l * (1 - l*2^-24)            (exact)
//   scale[l]  = (2^(l+4) - 1) - l*2^(l-20)     (exactly representable)
//   bits(scale[l]) = ((130+l)<<23) | (0x800000 - (0x100000>>l) - l)
// Separate mul/add (numpy does not fuse); __fdiv_rn for the normalize.
// Indices provably in [0, 2^19) -> '& (T-1)' == '% T'.
//
// R6 (this round): L1-BYPASS GATHERS. Falsified so far: gather latency (R4,
// 4x MLP ~= neutral), nt-store path (R5, plain ~= nt). Remaining model that
// fits all data: levels 8..15 are random over >32KiB working sets -> every
// probe misses L1 and pulls a full 128 B line from L2 to deliver 8 B
// (2^21 pts x 8 lines x 128 B ~= 2.2 GB on-chip, ~100 us at realistic L2
// random rate) — exactly the gap above the ~50 us request-rate floor.
// Fix: agent-scope relaxed loads (-> global_load_dwordx2 sc0) bypass L1;
// data returns at request granularity instead of line granularity. Request
// count unchanged, bytes/probe cut ~16x. Stores back to nt (R4 config) to
// keep the 268 MB write stream out of L2, which the gathers now lean on.

constexpr int T_SIZE = 524288;   // 2^19
constexpr int N_PTS  = 2097152;  // 2^21
constexpr int SLOTS  = N_PTS * 8;      // 2^24 float4 output slots
constexpr int KI     = 4;              // slots per thread
constexpr int NTH    = SLOTS / KI;     // 2^22 threads

typedef float vfloat4 __attribute__((ext_vector_type(4)));

__device__ __forceinline__ float scale_for_level(int l) {
    unsigned bits = ((130u + (unsigned)l) << 23)
                  | (0x800000u - (0x100000u >> l) - (unsigned)l);
    return __uint_as_float(bits);
}

__global__ __launch_bounds__(256) void hash_encode_kernel(
    const float* __restrict__ x,
    const float* __restrict__ table,
    const int* __restrict__ bound_p,
    float* __restrict__ out)
{
    int tid = blockIdx.x * 256 + threadIdx.x;   // 2^22 threads

    // NTH is a multiple of 8, so slot (tid + k*NTH) has the same low 3 bits
    // for all k: one level-pair (2j, 2j+1) per thread, scales computed once.
    int j  = tid & 7;
    int l0 = j << 1;
    float s0 = scale_for_level(l0);
    float s1 = scale_for_level(l0 + 1);

    float fb  = (float)bound_p[0];
    float fb2 = __fmul_rn(2.0f, fb);

    // Phase 1: all x loads in flight (streamed once, don't cache)
    float xv[KI];
#pragma unroll
    for (int k = 0; k < KI; ++k) {
        int n = (tid + k * NTH) >> 3;           // point index for slot k
        xv[k] = __builtin_nontemporal_load(&x[n]);
    }

    // Phase 2: indices. xs >= 0.5 always, so int-trunc == floor; result
    // < 2^19 so '&' is exact mod.
    int i0[KI], i1[KI];
#pragma unroll
    for (int k = 0; k < KI; ++k) {
        float xn  = __fdiv_rn(__fadd_rn(xv[k], fb), fb2);
        float xs0 = __fadd_rn(__fmul_rn(xn, s0), 0.5f);
        float xs1 = __fadd_rn(__fmul_rn(xn, s1), 0.5f);
        i0[k] = ((int)xs0) & (T_SIZE - 1);
        i1[k] = ((int)xs1) & (T_SIZE - 1);
    }

    // Phase 3: all 8 gathers back-to-back, L1-BYPASSED (sc0 via agent-scope
    // relaxed atomic load). Table entry = 8 B (float2) = one dwordx2; the
    // TCC returns only the requested bytes, not a 128 B line into L1.
    const unsigned long long* tq = (const unsigned long long*)table;
    unsigned long long a[KI], b[KI];
#pragma unroll
    for (int k = 0; k < KI; ++k) {
        a[k] = __hip_atomic_load(&tq[i0[k]], __ATOMIC_RELAXED,
                                 __HIP_MEMORY_SCOPE_AGENT);
        b[k] = __hip_atomic_load(&tq[i1[k]], __ATOMIC_RELAXED,
                                 __HIP_MEMORY_SCOPE_AGENT);
    }

    // Phase 4: coalesced nt stores (stream past L2: the gathers own L2 now)
#pragma unroll
    for (int k = 0; k < KI; ++k) {
        vfloat4 o;
        o.x = __uint_as_float((unsigned)(a[k]));
        o.y = __uint_as_float((unsigned)(a[k] >> 32));
        o.z = __uint_as_float((unsigned)(b[k]));
        o.w = __uint_as_float((unsigned)(b[k] >> 32));
        __builtin_nontemporal_store(o, (vfloat4*)out + (tid + k * NTH));
    }
}

extern "C" void kernel_launch(void* const* d_in, const int* in_sizes, int n_in,
                              void* d_out, int out_size, void* d_ws, size_t ws_size,
                              hipStream_t stream) {
    const float* x     = (const float*)d_in[0];
    const float* table = (const float*)d_in[1];
    const int*   bound = (const int*)d_in[2];
    float* out = (float*)d_out;

    int blocks = NTH / 256;                    // 16384
    hash_encode_kernel<<<blocks, 256, 0, stream>>>(x, table, bound, out);
}

// Round 4
// 341.288 us; speedup vs baseline: 1.0862x; 1.0862x over previous
//
#include <hip/hip_runtime.h>

// SimpleHashEncoder1D: out[n, l*2+f] = hash_table[floor(xn*scale[l]+0.5) & (T-1)][f]
// xn = (x+bound)/(2*bound), scale[l] = 16*b^l - 1, b = expf((logf(2^19)-logf(16))/15)
//
// float32 bit-exactness (verified R1, absmax == 0.0):
//   b = 0x3FFFFFFF = 2 - 2^-23   (NOT 2.0: correctly-rounded f32 log/exp chain)
//   fl32(b^l) = 2^l * (1 - l*2^-24)            (exact)
//   scale[l]  = (2^(l+4) - 1) - l*2^(l-20)     (exactly representable)
//   bits(scale[l]) = ((130+l)<<23) | (0x800000 - (0x100000>>l) - l)
// Separate mul/add (numpy does not fuse); __fdiv_rn for the normalize.
// Indices provably in [0, 2^19) -> '& (T-1)' == '% T'.
//
// Ledger: R4 (4x MLP) 338us best. R5 (plain stores) 344 ~ noise. R6 (sc0 on
// ALL levels) 371 — regression ~= cost of converting coarse-level L1 HITS
// into extra L2 probes, which CONFIRMS the L2 path is a serial term and L1
// hits relieve it.
//
// R7 (this round): SELECTIVE L1 bypass. Levels 0-9 (working sets <= 64 KiB,
// substantially L1-resident) keep plain cached loads = R4 behavior. Levels
// 10-15 (128 KiB..4 MiB, L1 hit <25%) use agent-scope relaxed loads
// (-> global_load_dwordx2 sc0): returns 8 B at request granularity instead
// of filling a 128 B line into L1 per probe, cutting ~1.6 GB of on-chip
// L2->L1 fill traffic while leaving L2 request count unchanged. The j>=5
// branch is lane-divergent: 2 half-wave gather instrs instead of 1 full,
// same TA segment count, issue rate is not the bottleneck.

constexpr int T_SIZE = 524288;   // 2^19
constexpr int N_PTS  = 2097152;  // 2^21
constexpr int SLOTS  = N_PTS * 8;      // 2^24 float4 output slots
constexpr int KI     = 4;              // slots per thread
constexpr int NTH    = SLOTS / KI;     // 2^22 threads

typedef float vfloat4 __attribute__((ext_vector_type(4)));

__device__ __forceinline__ float scale_for_level(int l) {
    unsigned bits = ((130u + (unsigned)l) << 23)
                  | (0x800000u - (0x100000u >> l) - (unsigned)l);
    return __uint_as_float(bits);
}

__global__ __launch_bounds__(256) void hash_encode_kernel(
    const float* __restrict__ x,
    const float* __restrict__ table,
    const int* __restrict__ bound_p,
    float* __restrict__ out)
{
    int tid = blockIdx.x * 256 + threadIdx.x;   // 2^22 threads

    // NTH is a multiple of 8, so slot (tid + k*NTH) has the same low 3 bits
    // for all k: one level-pair (2j, 2j+1) per thread, scales computed once.
    int j  = tid & 7;
    int l0 = j << 1;
    float s0 = scale_for_level(l0);
    float s1 = scale_for_level(l0 + 1);

    float fb  = (float)bound_p[0];
    float fb2 = __fmul_rn(2.0f, fb);

    // Phase 1: all x loads in flight (streamed once, don't cache; 8 lanes
    // share each address within one instruction -> single broadcast segment)
    float xv[KI];
#pragma unroll
    for (int k = 0; k < KI; ++k) {
        int n = (tid + k * NTH) >> 3;           // point index for slot k
        xv[k] = __builtin_nontemporal_load(&x[n]);
    }

    // Phase 2: indices. xs >= 0.5 always, so int-trunc == floor; result
    // < 2^19 so '&' is exact mod.
    int i0[KI], i1[KI];
#pragma unroll
    for (int k = 0; k < KI; ++k) {
        float xn  = __fdiv_rn(__fadd_rn(xv[k], fb), fb2);
        float xs0 = __fadd_rn(__fmul_rn(xn, s0), 0.5f);
        float xs1 = __fadd_rn(__fmul_rn(xn, s1), 0.5f);
        i0[k] = ((int)xs0) & (T_SIZE - 1);
        i1[k] = ((int)xs1) & (T_SIZE - 1);
    }

    // Phase 3: all 8 gathers back-to-back.
    //   j <  5 (levels 0..9, <=64 KiB working sets): plain cached loads —
    //          L1-resident, exactly the best-measured R4 path.
    //   j >= 5 (levels 10..15, 128 KiB..4 MiB): sc0 loads bypass L1, return
    //          8 B at request granularity, no 128 B line fill per probe.
    const unsigned long long* tq = (const unsigned long long*)table;
    unsigned long long a[KI], b[KI];
    if (j >= 5) {
#pragma unroll
        for (int k = 0; k < KI; ++k) {
            a[k] = __hip_atomic_load(&tq[i0[k]], __ATOMIC_RELAXED,
                                     __HIP_MEMORY_SCOPE_AGENT);
            b[k] = __hip_atomic_load(&tq[i1[k]], __ATOMIC_RELAXED,
                                     __HIP_MEMORY_SCOPE_AGENT);
        }
    } else {
#pragma unroll
        for (int k = 0; k < KI; ++k) {
            a[k] = tq[i0[k]];
            b[k] = tq[i1[k]];
        }
    }

    // Phase 4: coalesced nt stores (stream past L2: the gathers own L2)
#pragma unroll
    for (int k = 0; k < KI; ++k) {
        vfloat4 o;
        o.x = __uint_as_float((unsigned)(a[k]));
        o.y = __uint_as_float((unsigned)(a[k] >> 32));
        o.z = __uint_as_float((unsigned)(b[k]));
        o.w = __uint_as_float((unsigned)(b[k] >> 32));
        __builtin_nontemporal_store(o, (vfloat4*)out + (tid + k * NTH));
    }
}

extern "C" void kernel_launch(void* const* d_in, const int* in_sizes, int n_in,
                              void* d_out, int out_size, void* d_ws, size_t ws_size,
                              hipStream_t stream) {
    const float* x     = (const float*)d_in[0];
    const float* table = (const float*)d_in[1];
    const int*   bound = (const int*)d_in[2];
    float* out = (float*)d_out;

    int blocks = NTH / 256;                    // 16384
    hash_encode_kernel<<<blocks, 256, 0, stream>>>(x, table, bound, out);
}